// Round 5
// baseline (1429.272 us; speedup 1.0000x reference)
//
#include <hip/hip_runtime.h>

// LNN_50302656971188 — batched grad + partial-Hessian of 2-layer softmax MLP + 2x2 solve.
// R5: R4 showed ~45.5k VALU instr per 8-row batch vs ~20.8k structural — suspected
// AGPR spill round-trips (live state ~150 floats >> 104 VGPRs; gfx950 unified file
// spills VGPR->AGPR via v_accvgpr_*, invisible in VGPR_Count, zero HBM traffic).
// Fix under test: RPW 8->4 (live state ~85 floats, fits). Per-row arithmetic
// bit-identical to R4 (absmax must stay 5120).

#define RPW 4
#define NWAVES 8
#define NTHREADS 512
#define NGRID 256
#define NITERS 32      // 256 blocks * 8 waves * 4 rows * 32 = 262144
#define WSTRIDE 65     // float2 per j-row (64 + 1 pad)
#define LDS_BYTES (2 * 128 * WSTRIDE * 8)   // 133120 B

typedef float v2f __attribute__((ext_vector_type(2)));

__device__ __forceinline__ float rlane(float v, int l) {
    return __int_as_float(__builtin_amdgcn_readlane(__float_as_int(v), l));
}

// full-wave (64) sum reduction, all-VALU (DPP), result uniform
__device__ __forceinline__ float dppred(float x) {
    x += __int_as_float(__builtin_amdgcn_update_dpp(0, __float_as_int(x), 0x111, 0xf, 0xf, true)); // row_shr:1
    x += __int_as_float(__builtin_amdgcn_update_dpp(0, __float_as_int(x), 0x112, 0xf, 0xf, true)); // row_shr:2
    x += __int_as_float(__builtin_amdgcn_update_dpp(0, __float_as_int(x), 0x114, 0xf, 0xf, true)); // row_shr:4
    x += __int_as_float(__builtin_amdgcn_update_dpp(0, __float_as_int(x), 0x118, 0xf, 0xf, true)); // row_shr:8
    x += __int_as_float(__builtin_amdgcn_update_dpp(0, __float_as_int(x), 0x142, 0xa, 0xf, true)); // bcast15
    x += __int_as_float(__builtin_amdgcn_update_dpp(0, __float_as_int(x), 0x143, 0xc, 0xf, true)); // bcast31
    return rlane(x, 63);
}

// acc{a,b}[r] += W * s[r]; W pre-paired: Wb[j*WSTRIDE + lane] = {W[lane][j], W[lane+64][j]}
// s distributed: s0[r] lane j holds s_j (j<64), s1[r] lane j holds s_{j+64}
__device__ __forceinline__ void mv1(const v2f* __restrict__ Wb, int lane,
                                    const float (&s0)[RPW], const float (&s1)[RPW],
                                    float (&za)[RPW], float (&zb)[RPW])
{
    const v2f* wp = Wb + lane;
#pragma unroll 4
    for (int j = 0; j < 64; ++j) {
        const v2f w = wp[j * WSTRIDE];
#pragma unroll
        for (int r = 0; r < RPW; ++r) {
            const float s = rlane(s0[r], j);        // SGPR
            za[r] = fmaf(w.x, s, za[r]);            // v_fma_f32 v,v,s,v
            zb[r] = fmaf(w.y, s, zb[r]);
        }
    }
#pragma unroll 4
    for (int j = 0; j < 64; ++j) {
        const v2f w = wp[(64 + j) * WSTRIDE];
#pragma unroll
        for (int r = 0; r < RPW; ++r) {
            const float s = rlane(s1[r], j);
            za[r] = fmaf(w.x, s, za[r]);
            zb[r] = fmaf(w.y, s, zb[r]);
        }
    }
}

// dual: two s-vectors share each weight read (HVP tangent fusion)
__device__ __forceinline__ void mv2(const v2f* __restrict__ Wb, int lane,
                                    const float (&a0)[RPW], const float (&a1)[RPW],
                                    const float (&b0)[RPW], const float (&b1)[RPW],
                                    float (&zAa)[RPW], float (&zAb)[RPW],
                                    float (&zBa)[RPW], float (&zBb)[RPW])
{
    const v2f* wp = Wb + lane;
#pragma unroll 4
    for (int j = 0; j < 64; ++j) {
        const v2f w = wp[j * WSTRIDE];
#pragma unroll
        for (int r = 0; r < RPW; ++r) {
            const float sa = rlane(a0[r], j);
            const float sb = rlane(b0[r], j);
            zAa[r] = fmaf(w.x, sa, zAa[r]);
            zAb[r] = fmaf(w.y, sa, zAb[r]);
            zBa[r] = fmaf(w.x, sb, zBa[r]);
            zBb[r] = fmaf(w.y, sb, zBb[r]);
        }
    }
#pragma unroll 4
    for (int j = 0; j < 64; ++j) {
        const v2f w = wp[(64 + j) * WSTRIDE];
#pragma unroll
        for (int r = 0; r < RPW; ++r) {
            const float sa = rlane(a1[r], j);
            const float sb = rlane(b1[r], j);
            zAa[r] = fmaf(w.x, sa, zAa[r]);
            zAb[r] = fmaf(w.y, sa, zAb[r]);
            zBa[r] = fmaf(w.x, sb, zBa[r]);
            zBb[r] = fmaf(w.y, sb, zBb[r]);
        }
    }
}

extern "C" __global__ __launch_bounds__(NTHREADS, 2)
void lnn_kernel(const float* __restrict__ gx, const float* __restrict__ gW1,
                const float* __restrict__ gb1, const float* __restrict__ gW2,
                const float* __restrict__ gb2, const float* __restrict__ gW3,
                float* __restrict__ gout)
{
    extern __shared__ float lds[];
    v2f* Wp  = (v2f*)lds;                      // fwd: Wp[j][l]  = {W[l][j],  W[l+64][j]}
    v2f* Wtp = Wp + 128 * WSTRIDE;             // tr:  Wtp[i][l] = {W[i][l],  W[i][l+64]}

    const int tid  = threadIdx.x;
    const int lane = tid & 63;
    const int wv   = tid >> 6;

    for (int e = tid; e < 16384; e += NTHREADS) {
        const int i = e >> 7, j = e & 127;
        const float w = gW2[e];
        ((float*)Wp)[(j * WSTRIDE + (i & 63)) * 2 + (i >> 6)] = w;
        ((float*)Wtp)[(i * WSTRIDE + (j & 63)) * 2 + (j >> 6)] = w;
    }

    const int cA = lane, cB = lane + 64;
    const float w1a0 = gW1[cA * 4 + 0], w1a1 = gW1[cA * 4 + 1],
                w1a2 = gW1[cA * 4 + 2], w1a3 = gW1[cA * 4 + 3];
    const float w1b0 = gW1[cB * 4 + 0], w1b1 = gW1[cB * 4 + 1],
                w1b2 = gW1[cB * 4 + 2], w1b3 = gW1[cB * 4 + 3];
    const float b1a = gb1[cA], b1b = gb1[cB];
    const float b2a = gb2[cA], b2b = gb2[cB];
    const float w3a = gW3[cA], w3b = gW3[cB];

    __syncthreads();   // weights staged; no further barriers

#pragma unroll 1
    for (int it = 0; it < NITERS; ++it) {
        const int row0 = blockIdx.x * (NITERS * NWAVES * RPW) + it * (NWAVES * RPW) + wv * RPW;

        float p0[RPW], p1[RPW], q0[RPW], q1[RPW], v0[RPW], v1[RPW];
        float X2[RPW], X3[RPW];
        float sw[RPW], pv[RPW], g0[RPW];

        // ---- layer 1: p = softmax(W1 x + b1)
#pragma unroll
        for (int r = 0; r < RPW; ++r) {
            const float4 xr = ((const float4*)gx)[row0 + r];
            X2[r] = xr.z; X3[r] = xr.w;
            const float z1a = fmaf(w1a0, xr.x, fmaf(w1a1, xr.y, fmaf(w1a2, xr.z, fmaf(w1a3, xr.w, b1a))));
            const float z1b = fmaf(w1b0, xr.x, fmaf(w1b1, xr.y, fmaf(w1b2, xr.z, fmaf(w1b3, xr.w, b1b))));
            const float ea = __expf(z1a), eb = __expf(z1b);
            const float rs = 1.0f / dppred(ea + eb);
            p0[r] = ea * rs; p1[r] = eb * rs;
        }

        // ---- layer 2 forward: z = W2 p + b2 ; q = softmax(z); u = q*(w3 - s)
        float zfa[RPW], zfb[RPW];
#pragma unroll
        for (int r = 0; r < RPW; ++r) { zfa[r] = b2a; zfb[r] = b2b; }
        mv1(Wp, lane, p0, p1, zfa, zfb);
        float u0[RPW], u1[RPW];
#pragma unroll
        for (int r = 0; r < RPW; ++r) {
            const float ea = __expf(zfa[r]), eb = __expf(zfb[r]);
            const float rs = 1.0f / dppred(ea + eb);
            q0[r] = ea * rs; q1[r] = eb * rs;
            sw[r] = dppred(fmaf(w3a, q0[r], w3b * q1[r]));
            u0[r] = q0[r] * (w3a - sw[r]);
            u1[r] = q1[r] * (w3b - sw[r]);
        }

        // ---- backward: v = W2^T u ; pv = p.v ; g0 = W1[:,0] . (p*(v-pv))
#pragma unroll
        for (int r = 0; r < RPW; ++r) { zfa[r] = 0.f; zfb[r] = 0.f; }
        mv1(Wtp, lane, u0, u1, zfa, zfb);
#pragma unroll
        for (int r = 0; r < RPW; ++r) {
            v0[r] = zfa[r]; v1[r] = zfb[r];
            pv[r] = dppred(fmaf(p0[r], v0[r], p1[r] * v1[r]));
            g0[r] = dppred(fmaf(w1a0, p0[r] * (v0[r] - pv[r]), w1b0 * (p1[r] * (v1[r] - pv[r]))));
        }

        // ---- dual HVP: tangents t2 = W1[:,2], t3 = W1[:,3]
        float pd20[RPW], pd21[RPW], pd30[RPW], pd31[RPW];
#pragma unroll
        for (int r = 0; r < RPW; ++r) {
            const float pi2 = dppred(fmaf(w1a2, p0[r], w1b2 * p1[r]));
            const float pi3 = dppred(fmaf(w1a3, p0[r], w1b3 * p1[r]));
            pd20[r] = p0[r] * (w1a2 - pi2); pd21[r] = p1[r] * (w1b2 - pi2);
            pd30[r] = p0[r] * (w1a3 - pi3); pd31[r] = p1[r] * (w1b3 - pi3);
        }
        float z2a[RPW], z2b[RPW], z3a[RPW], z3b[RPW];
#pragma unroll
        for (int r = 0; r < RPW; ++r) { z2a[r] = 0.f; z2b[r] = 0.f; z3a[r] = 0.f; z3b[r] = 0.f; }
        mv2(Wp, lane, pd20, pd21, pd30, pd31, z2a, z2b, z3a, z3b);   // zdot = W2 pdot

        float ud20[RPW], ud21[RPW], ud30[RPW], ud31[RPW];
#pragma unroll
        for (int r = 0; r < RPW; ++r) {
            const float zd20 = z2a[r], zd21 = z2b[r];
            const float zd30 = z3a[r], zd31 = z3b[r];
            const float sg2 = dppred(fmaf(q0[r], zd20, q1[r] * zd21));
            const float sg3 = dppred(fmaf(q0[r], zd30, q1[r] * zd31));
            const float qd20 = q0[r] * (zd20 - sg2), qd21 = q1[r] * (zd21 - sg2);
            const float qd30 = q0[r] * (zd30 - sg3), qd31 = q1[r] * (zd31 - sg3);
            const float sd2 = dppred(fmaf(w3a, qd20, w3b * qd21));
            const float sd3 = dppred(fmaf(w3a, qd30, w3b * qd31));
            ud20[r] = fmaf(qd20, w3a - sw[r], -(q0[r] * sd2));
            ud21[r] = fmaf(qd21, w3b - sw[r], -(q1[r] * sd2));
            ud30[r] = fmaf(qd30, w3a - sw[r], -(q0[r] * sd3));
            ud31[r] = fmaf(qd31, w3b - sw[r], -(q1[r] * sd3));
        }
#pragma unroll
        for (int r = 0; r < RPW; ++r) { z2a[r] = 0.f; z2b[r] = 0.f; z3a[r] = 0.f; z3b[r] = 0.f; }
        mv2(Wtp, lane, ud20, ud21, ud30, ud31, z2a, z2b, z3a, z3b);  // vdot = W2^T udot

#pragma unroll
        for (int r = 0; r < RPW; ++r) {
            const float vd20 = z2a[r], vd21 = z2b[r];
            const float vd30 = z3a[r], vd31 = z3b[r];
            const float dpv2 = dppred(fmaf(pd20[r], v0[r], fmaf(pd21[r], v1[r],
                               fmaf(p0[r], vd20, p1[r] * vd21))));
            const float dpv3 = dppred(fmaf(pd30[r], v0[r], fmaf(pd31[r], v1[r],
                               fmaf(p0[r], vd30, p1[r] * vd31))));
            const float gd20 = fmaf(pd20[r], v0[r] - pv[r], p0[r] * (vd20 - dpv2));
            const float gd21 = fmaf(pd21[r], v1[r] - pv[r], p1[r] * (vd21 - dpv2));
            const float gd30 = fmaf(pd30[r], v0[r] - pv[r], p0[r] * (vd30 - dpv3));
            const float gd31 = fmaf(pd31[r], v1[r] - pv[r], p1[r] * (vd31 - dpv3));
            const float h20 = dppred(fmaf(w1a0, gd20, w1b0 * gd21));
            const float h21 = dppred(fmaf(w1a1, gd20, w1b1 * gd21));
            const float h22 = dppred(fmaf(w1a2, gd20, w1b2 * gd21));
            const float h23 = dppred(fmaf(w1a3, gd20, w1b3 * gd21));
            const float h30 = dppred(fmaf(w1a0, gd30, w1b0 * gd31));
            const float h31 = dppred(fmaf(w1a1, gd30, w1b1 * gd31));
            const float h32 = dppred(fmaf(w1a2, gd30, w1b2 * gd31));
            const float h33 = dppred(fmaf(w1a3, gd30, w1b3 * gd31));

            // ---- 2x2 solve in fp64 (cheap; det cancellation is the error amplifier)
            const double rhs0 = (double)g0[r] - ((double)h20 * (double)X2[r] + (double)h21 * (double)X3[r]);
            const double rhs1 = (double)g0[r] - ((double)h30 * (double)X2[r] + (double)h31 * (double)X3[r]);
            const double a = (double)h22, b = (double)h32, c = (double)h23, d = (double)h33;
            const double det = a * d - b * c;
            const float t0 = (float)((d * rhs0 - b * rhs1) / det);
            const float t1 = (float)((a * rhs1 - c * rhs0) / det);
            if (lane == 0) {
                ((float4*)gout)[row0 + r] = make_float4(X2[r], X3[r], t0, t1);
            }
        }
    }
}

extern "C" void kernel_launch(void* const* d_in, const int* in_sizes, int n_in,
                              void* d_out, int out_size, void* d_ws, size_t ws_size,
                              hipStream_t stream)
{
    const float* gx  = (const float*)d_in[0];
    const float* gW1 = (const float*)d_in[1];
    const float* gb1 = (const float*)d_in[2];
    const float* gW2 = (const float*)d_in[3];
    const float* gb2 = (const float*)d_in[4];
    const float* gW3 = (const float*)d_in[5];
    float* gout = (float*)d_out;

    (void)hipFuncSetAttribute((const void*)lnn_kernel,
                              hipFuncAttributeMaxDynamicSharedMemorySize, LDS_BYTES);
    lnn_kernel<<<NGRID, NTHREADS, LDS_BYTES, stream>>>(gx, gW1, gb1, gW2, gb2, gW3, gout);
}

// Round 7
// 1188.000 us; speedup vs baseline: 1.2031x; 1.2031x over previous
//
#include <hip/hip_runtime.h>

// LNN_50302656971188 — batched grad + partial-Hessian of 2-layer softmax MLP + 2x2 solve.
// R7: R6's only numeric change (transpose interleave) broke absmax (8192>5407). Restore
// R4's exact summation order (i=0..63 then 64..127 single chain) while keeping LDS
// broadcast staging (the R3-R5 readlane bottleneck fix). Weight layout: W2 as four
// 64x64 quadrants, row-major stride 65 — row reads (fwd) AND col reads (transpose)
// are both bank-(lane+k)%32 = 2-way = free, and both walk indices sequentially.

#define RPW 8
#define NWAVES 8
#define NTHREADS 512
#define NGRID 256
#define NITERS 16      // 256 blocks * 8 waves * 8 rows * 16 = 262144
#define QSTRIDE 65
#define QSIZE (64 * QSTRIDE)                              // 4160 floats per quadrant
#define LDS_FLOATS (4 * QSIZE + NWAVES * 2 * RPW * 128)   // 16640 + 16384 = 33024
#define LDS_BYTES (LDS_FLOATS * 4)                        // 132096 B

__device__ __forceinline__ float rlane(float v, int l) {
    return __int_as_float(__builtin_amdgcn_readlane(__float_as_int(v), l));
}

// full-wave (64) sum reduction via DPP, result uniform (identical to R3-R5: absmax-safe)
__device__ __forceinline__ float dppred(float x) {
    x += __int_as_float(__builtin_amdgcn_update_dpp(0, __float_as_int(x), 0x111, 0xf, 0xf, true)); // row_shr:1
    x += __int_as_float(__builtin_amdgcn_update_dpp(0, __float_as_int(x), 0x112, 0xf, 0xf, true)); // row_shr:2
    x += __int_as_float(__builtin_amdgcn_update_dpp(0, __float_as_int(x), 0x114, 0xf, 0xf, true)); // row_shr:4
    x += __int_as_float(__builtin_amdgcn_update_dpp(0, __float_as_int(x), 0x118, 0xf, 0xf, true)); // row_shr:8
    x += __int_as_float(__builtin_amdgcn_update_dpp(0, __float_as_int(x), 0x142, 0xa, 0xf, true)); // bcast15
    x += __int_as_float(__builtin_amdgcn_update_dpp(0, __float_as_int(x), 0x143, 0xc, 0xf, true)); // bcast31
    return rlane(x, 63);
}

// Quadrant layout: Wq[(a*2+b)*QSIZE + r*QSTRIDE + c] = W2[a*64+r][b*64+c]

// ---- forward: z_cA += W2[lane][j] s_j ; z_cB += W2[lane+64][j] s_j ; j = 0..63 then 64..127
__device__ __forceinline__ void mvf(const float* __restrict__ Wq,
                                    const float* __restrict__ S, int lane,
                                    float (&za)[RPW], float (&zb)[RPW])
{
    const float* w00 = Wq + 0 * QSIZE + lane * QSTRIDE;
    const float* w01 = Wq + 1 * QSIZE + lane * QSTRIDE;
    const float* w10 = Wq + 2 * QSIZE + lane * QSTRIDE;
    const float* w11 = Wq + 3 * QSIZE + lane * QSTRIDE;
#pragma unroll 2
    for (int j = 0; j < 64; j += 4) {
        const float a0 = w00[j], a1 = w00[j+1], a2 = w00[j+2], a3 = w00[j+3];
        const float b0 = w10[j], b1 = w10[j+1], b2 = w10[j+2], b3 = w10[j+3];
#pragma unroll
        for (int r = 0; r < RPW; ++r) {
            const float4 s4 = *(const float4*)(S + r * 128 + j);   // broadcast
            za[r] = fmaf(a0, s4.x, za[r]); za[r] = fmaf(a1, s4.y, za[r]);
            za[r] = fmaf(a2, s4.z, za[r]); za[r] = fmaf(a3, s4.w, za[r]);
            zb[r] = fmaf(b0, s4.x, zb[r]); zb[r] = fmaf(b1, s4.y, zb[r]);
            zb[r] = fmaf(b2, s4.z, zb[r]); zb[r] = fmaf(b3, s4.w, zb[r]);
        }
    }
#pragma unroll 2
    for (int j = 0; j < 64; j += 4) {
        const float a0 = w01[j], a1 = w01[j+1], a2 = w01[j+2], a3 = w01[j+3];
        const float b0 = w11[j], b1 = w11[j+1], b2 = w11[j+2], b3 = w11[j+3];
#pragma unroll
        for (int r = 0; r < RPW; ++r) {
            const float4 s4 = *(const float4*)(S + r * 128 + 64 + j);
            za[r] = fmaf(a0, s4.x, za[r]); za[r] = fmaf(a1, s4.y, za[r]);
            za[r] = fmaf(a2, s4.z, za[r]); za[r] = fmaf(a3, s4.w, za[r]);
            zb[r] = fmaf(b0, s4.x, zb[r]); zb[r] = fmaf(b1, s4.y, zb[r]);
            zb[r] = fmaf(b2, s4.z, zb[r]); zb[r] = fmaf(b3, s4.w, zb[r]);
        }
    }
}

// dual-s forward (weights read once for two s-vectors)
__device__ __forceinline__ void mvf2(const float* __restrict__ Wq,
                                     const float* __restrict__ SA,
                                     const float* __restrict__ SB, int lane,
                                     float (&zAa)[RPW], float (&zAb)[RPW],
                                     float (&zBa)[RPW], float (&zBb)[RPW])
{
    const float* w00 = Wq + 0 * QSIZE + lane * QSTRIDE;
    const float* w01 = Wq + 1 * QSIZE + lane * QSTRIDE;
    const float* w10 = Wq + 2 * QSIZE + lane * QSTRIDE;
    const float* w11 = Wq + 3 * QSIZE + lane * QSTRIDE;
#pragma unroll 2
    for (int j = 0; j < 64; j += 4) {
        const float a0 = w00[j], a1 = w00[j+1], a2 = w00[j+2], a3 = w00[j+3];
        const float b0 = w10[j], b1 = w10[j+1], b2 = w10[j+2], b3 = w10[j+3];
#pragma unroll
        for (int r = 0; r < RPW; ++r) {
            const float4 x4 = *(const float4*)(SA + r * 128 + j);
            const float4 y4 = *(const float4*)(SB + r * 128 + j);
            zAa[r] = fmaf(a0, x4.x, zAa[r]); zAa[r] = fmaf(a1, x4.y, zAa[r]);
            zAa[r] = fmaf(a2, x4.z, zAa[r]); zAa[r] = fmaf(a3, x4.w, zAa[r]);
            zAb[r] = fmaf(b0, x4.x, zAb[r]); zAb[r] = fmaf(b1, x4.y, zAb[r]);
            zAb[r] = fmaf(b2, x4.z, zAb[r]); zAb[r] = fmaf(b3, x4.w, zAb[r]);
            zBa[r] = fmaf(a0, y4.x, zBa[r]); zBa[r] = fmaf(a1, y4.y, zBa[r]);
            zBa[r] = fmaf(a2, y4.z, zBa[r]); zBa[r] = fmaf(a3, y4.w, zBa[r]);
            zBb[r] = fmaf(b0, y4.x, zBb[r]); zBb[r] = fmaf(b1, y4.y, zBb[r]);
            zBb[r] = fmaf(b2, y4.z, zBb[r]); zBb[r] = fmaf(b3, y4.w, zBb[r]);
        }
    }
#pragma unroll 2
    for (int j = 0; j < 64; j += 4) {
        const float a0 = w01[j], a1 = w01[j+1], a2 = w01[j+2], a3 = w01[j+3];
        const float b0 = w11[j], b1 = w11[j+1], b2 = w11[j+2], b3 = w11[j+3];
#pragma unroll
        for (int r = 0; r < RPW; ++r) {
            const float4 x4 = *(const float4*)(SA + r * 128 + 64 + j);
            const float4 y4 = *(const float4*)(SB + r * 128 + 64 + j);
            zAa[r] = fmaf(a0, x4.x, zAa[r]); zAa[r] = fmaf(a1, x4.y, zAa[r]);
            zAa[r] = fmaf(a2, x4.z, zAa[r]); zAa[r] = fmaf(a3, x4.w, zAa[r]);
            zAb[r] = fmaf(b0, x4.x, zAb[r]); zAb[r] = fmaf(b1, x4.y, zAb[r]);
            zAb[r] = fmaf(b2, x4.z, zAb[r]); zAb[r] = fmaf(b3, x4.w, zAb[r]);
            zBa[r] = fmaf(a0, y4.x, zBa[r]); zBa[r] = fmaf(a1, y4.y, zBa[r]);
            zBa[r] = fmaf(a2, y4.z, zBa[r]); zBa[r] = fmaf(a3, y4.w, zBa[r]);
            zBb[r] = fmaf(b0, y4.x, zBb[r]); zBb[r] = fmaf(b1, y4.y, zBb[r]);
            zBb[r] = fmaf(b2, y4.z, zBb[r]); zBb[r] = fmaf(b3, y4.w, zBb[r]);
        }
    }
}

// ---- transpose: v_cA += W2[i][lane] u_i ; v_cB += W2[i][lane+64] u_i ; i = 0..63 then 64..127
__device__ __forceinline__ void mvt(const float* __restrict__ Wq,
                                    const float* __restrict__ S, int lane,
                                    float (&za)[RPW], float (&zb)[RPW])
{
    const float* t00 = Wq + 0 * QSIZE + lane;   // col lane of Q00 (rows 0..63)
    const float* t01 = Wq + 1 * QSIZE + lane;   // col lane of Q01 (= col lane+64 of W2)
    const float* t10 = Wq + 2 * QSIZE + lane;   // rows 64..127, col lane
    const float* t11 = Wq + 3 * QSIZE + lane;
#pragma unroll 2
    for (int i = 0; i < 64; i += 4) {
        const float a0 = t00[(i+0)*QSTRIDE], a1 = t00[(i+1)*QSTRIDE],
                    a2 = t00[(i+2)*QSTRIDE], a3 = t00[(i+3)*QSTRIDE];
        const float b0 = t01[(i+0)*QSTRIDE], b1 = t01[(i+1)*QSTRIDE],
                    b2 = t01[(i+2)*QSTRIDE], b3 = t01[(i+3)*QSTRIDE];
#pragma unroll
        for (int r = 0; r < RPW; ++r) {
            const float4 u4 = *(const float4*)(S + r * 128 + i);
            za[r] = fmaf(a0, u4.x, za[r]); za[r] = fmaf(a1, u4.y, za[r]);
            za[r] = fmaf(a2, u4.z, za[r]); za[r] = fmaf(a3, u4.w, za[r]);
            zb[r] = fmaf(b0, u4.x, zb[r]); zb[r] = fmaf(b1, u4.y, zb[r]);
            zb[r] = fmaf(b2, u4.z, zb[r]); zb[r] = fmaf(b3, u4.w, zb[r]);
        }
    }
#pragma unroll 2
    for (int i = 0; i < 64; i += 4) {
        const float a0 = t10[(i+0)*QSTRIDE], a1 = t10[(i+1)*QSTRIDE],
                    a2 = t10[(i+2)*QSTRIDE], a3 = t10[(i+3)*QSTRIDE];
        const float b0 = t11[(i+0)*QSTRIDE], b1 = t11[(i+1)*QSTRIDE],
                    b2 = t11[(i+2)*QSTRIDE], b3 = t11[(i+3)*QSTRIDE];
#pragma unroll
        for (int r = 0; r < RPW; ++r) {
            const float4 u4 = *(const float4*)(S + r * 128 + 64 + i);
            za[r] = fmaf(a0, u4.x, za[r]); za[r] = fmaf(a1, u4.y, za[r]);
            za[r] = fmaf(a2, u4.z, za[r]); za[r] = fmaf(a3, u4.w, za[r]);
            zb[r] = fmaf(b0, u4.x, zb[r]); zb[r] = fmaf(b1, u4.y, zb[r]);
            zb[r] = fmaf(b2, u4.z, zb[r]); zb[r] = fmaf(b3, u4.w, zb[r]);
        }
    }
}

__device__ __forceinline__ void mvt2(const float* __restrict__ Wq,
                                     const float* __restrict__ SA,
                                     const float* __restrict__ SB, int lane,
                                     float (&zAa)[RPW], float (&zAb)[RPW],
                                     float (&zBa)[RPW], float (&zBb)[RPW])
{
    const float* t00 = Wq + 0 * QSIZE + lane;
    const float* t01 = Wq + 1 * QSIZE + lane;
    const float* t10 = Wq + 2 * QSIZE + lane;
    const float* t11 = Wq + 3 * QSIZE + lane;
#pragma unroll 2
    for (int i = 0; i < 64; i += 4) {
        const float a0 = t00[(i+0)*QSTRIDE], a1 = t00[(i+1)*QSTRIDE],
                    a2 = t00[(i+2)*QSTRIDE], a3 = t00[(i+3)*QSTRIDE];
        const float b0 = t01[(i+0)*QSTRIDE], b1 = t01[(i+1)*QSTRIDE],
                    b2 = t01[(i+2)*QSTRIDE], b3 = t01[(i+3)*QSTRIDE];
#pragma unroll
        for (int r = 0; r < RPW; ++r) {
            const float4 x4 = *(const float4*)(SA + r * 128 + i);
            const float4 y4 = *(const float4*)(SB + r * 128 + i);
            zAa[r] = fmaf(a0, x4.x, zAa[r]); zAa[r] = fmaf(a1, x4.y, zAa[r]);
            zAa[r] = fmaf(a2, x4.z, zAa[r]); zAa[r] = fmaf(a3, x4.w, zAa[r]);
            zAb[r] = fmaf(b0, x4.x, zAb[r]); zAb[r] = fmaf(b1, x4.y, zAb[r]);
            zAb[r] = fmaf(b2, x4.z, zAb[r]); zAb[r] = fmaf(b3, x4.w, zAb[r]);
            zBa[r] = fmaf(a0, y4.x, zBa[r]); zBa[r] = fmaf(a1, y4.y, zBa[r]);
            zBa[r] = fmaf(a2, y4.z, zBa[r]); zBa[r] = fmaf(a3, y4.w, zBa[r]);
            zBb[r] = fmaf(b0, y4.x, zBb[r]); zBb[r] = fmaf(b1, y4.y, zBb[r]);
            zBb[r] = fmaf(b2, y4.z, zBb[r]); zBb[r] = fmaf(b3, y4.w, zBb[r]);
        }
    }
#pragma unroll 2
    for (int i = 0; i < 64; i += 4) {
        const float a0 = t10[(i+0)*QSTRIDE], a1 = t10[(i+1)*QSTRIDE],
                    a2 = t10[(i+2)*QSTRIDE], a3 = t10[(i+3)*QSTRIDE];
        const float b0 = t11[(i+0)*QSTRIDE], b1 = t11[(i+1)*QSTRIDE],
                    b2 = t11[(i+2)*QSTRIDE], b3 = t11[(i+3)*QSTRIDE];
#pragma unroll
        for (int r = 0; r < RPW; ++r) {
            const float4 x4 = *(const float4*)(SA + r * 128 + 64 + i);
            const float4 y4 = *(const float4*)(SB + r * 128 + 64 + i);
            zAa[r] = fmaf(a0, x4.x, zAa[r]); zAa[r] = fmaf(a1, x4.y, zAa[r]);
            zAa[r] = fmaf(a2, x4.z, zAa[r]); zAa[r] = fmaf(a3, x4.w, zAa[r]);
            zAb[r] = fmaf(b0, x4.x, zAb[r]); zAb[r] = fmaf(b1, x4.y, zAb[r]);
            zAb[r] = fmaf(b2, x4.z, zAb[r]); zAb[r] = fmaf(b3, x4.w, zAb[r]);
            zBa[r] = fmaf(a0, y4.x, zBa[r]); zBa[r] = fmaf(a1, y4.y, zBa[r]);
            zBa[r] = fmaf(a2, y4.z, zBa[r]); zBa[r] = fmaf(a3, y4.w, zBa[r]);
            zBb[r] = fmaf(b0, y4.x, zBb[r]); zBb[r] = fmaf(b1, y4.y, zBb[r]);
            zBb[r] = fmaf(b2, y4.z, zBb[r]); zBb[r] = fmaf(b3, y4.w, zBb[r]);
        }
    }
}

extern "C" __global__ __launch_bounds__(NTHREADS, 2)
void lnn_kernel(const float* __restrict__ gx, const float* __restrict__ gW1,
                const float* __restrict__ gb1, const float* __restrict__ gW2,
                const float* __restrict__ gb2, const float* __restrict__ gW3,
                float* __restrict__ gout)
{
    extern __shared__ float lds[];
    float* Wq  = lds;                     // 4 quadrants, each [64][QSTRIDE]
    float* Sst = lds + 4 * QSIZE;         // [NWAVES][2][RPW][128] staging

    const int tid  = threadIdx.x;
    const int lane = tid & 63;
    const int wv   = tid >> 6;

    for (int e = tid; e < 16384; e += NTHREADS) {
        const int i = e >> 7, j = e & 127;
        Wq[((i >> 6) * 2 + (j >> 6)) * QSIZE + (i & 63) * QSTRIDE + (j & 63)] = gW2[e];
    }

    const int cA = lane, cB = lane + 64;
    const float w1a0 = gW1[cA * 4 + 0], w1a1 = gW1[cA * 4 + 1],
                w1a2 = gW1[cA * 4 + 2], w1a3 = gW1[cA * 4 + 3];
    const float w1b0 = gW1[cB * 4 + 0], w1b1 = gW1[cB * 4 + 1],
                w1b2 = gW1[cB * 4 + 2], w1b3 = gW1[cB * 4 + 3];
    const float b1a = gb1[cA], b1b = gb1[cB];
    const float b2a = gb2[cA], b2b = gb2[cB];
    const float w3a = gW3[cA], w3b = gW3[cB];

    __syncthreads();   // weights staged; Sa/Sb below are wave-private

    float* Sa = Sst + wv * (2 * RPW * 128);
    float* Sb = Sa + RPW * 128;

#pragma unroll 1
    for (int it = 0; it < NITERS; ++it) {
        const int row0 = blockIdx.x * (NITERS * NWAVES * RPW) + it * (NWAVES * RPW) + wv * RPW;

        float p0[RPW], p1[RPW], q0[RPW], q1[RPW], v0[RPW], v1[RPW];
        float X2[RPW], X3[RPW];
        float sw[RPW], pv[RPW], g0[RPW];

        // ---- layer 1: p = softmax(W1 x + b1); stage p into Sa
#pragma unroll
        for (int r = 0; r < RPW; ++r) {
            const float4 xr = ((const float4*)gx)[row0 + r];
            X2[r] = xr.z; X3[r] = xr.w;
            const float z1a = fmaf(w1a0, xr.x, fmaf(w1a1, xr.y, fmaf(w1a2, xr.z, fmaf(w1a3, xr.w, b1a))));
            const float z1b = fmaf(w1b0, xr.x, fmaf(w1b1, xr.y, fmaf(w1b2, xr.z, fmaf(w1b3, xr.w, b1b))));
            const float ea = __expf(z1a), eb = __expf(z1b);
            const float rs = 1.0f / dppred(ea + eb);
            p0[r] = ea * rs; p1[r] = eb * rs;
            Sa[r * 128 + lane]      = p0[r];
            Sa[r * 128 + 64 + lane] = p1[r];
        }

        // ---- layer 2 forward: z = W2 p + b2 ; q = softmax(z); u = q*(w3 - s)
        float zfa[RPW], zfb[RPW];
#pragma unroll
        for (int r = 0; r < RPW; ++r) { zfa[r] = b2a; zfb[r] = b2b; }
        mvf(Wq, Sa, lane, zfa, zfb);
#pragma unroll
        for (int r = 0; r < RPW; ++r) {
            const float ea = __expf(zfa[r]), eb = __expf(zfb[r]);
            const float rs = 1.0f / dppred(ea + eb);
            q0[r] = ea * rs; q1[r] = eb * rs;
            sw[r] = dppred(fmaf(w3a, q0[r], w3b * q1[r]));
            Sa[r * 128 + lane]      = q0[r] * (w3a - sw[r]);   // u
            Sa[r * 128 + 64 + lane] = q1[r] * (w3b - sw[r]);
        }

        // ---- backward: v = W2^T u ; pv = p.v ; g0 = W1[:,0] . (p*(v-pv))
#pragma unroll
        for (int r = 0; r < RPW; ++r) { zfa[r] = 0.f; zfb[r] = 0.f; }
        mvt(Wq, Sa, lane, zfa, zfb);
#pragma unroll
        for (int r = 0; r < RPW; ++r) {
            v0[r] = zfa[r]; v1[r] = zfb[r];
            pv[r] = dppred(fmaf(p0[r], v0[r], p1[r] * v1[r]));
            g0[r] = dppred(fmaf(w1a0, p0[r] * (v0[r] - pv[r]), w1b0 * (p1[r] * (v1[r] - pv[r]))));
        }

        // ---- dual HVP: tangents t2 = W1[:,2], t3 = W1[:,3]; stage pd2->Sa, pd3->Sb
        float pd20[RPW], pd21[RPW], pd30[RPW], pd31[RPW];
#pragma unroll
        for (int r = 0; r < RPW; ++r) {
            const float pi2 = dppred(fmaf(w1a2, p0[r], w1b2 * p1[r]));
            const float pi3 = dppred(fmaf(w1a3, p0[r], w1b3 * p1[r]));
            pd20[r] = p0[r] * (w1a2 - pi2); pd21[r] = p1[r] * (w1b2 - pi2);
            pd30[r] = p0[r] * (w1a3 - pi3); pd31[r] = p1[r] * (w1b3 - pi3);
            Sa[r * 128 + lane]      = pd20[r];
            Sa[r * 128 + 64 + lane] = pd21[r];
            Sb[r * 128 + lane]      = pd30[r];
            Sb[r * 128 + 64 + lane] = pd31[r];
        }
        float z2a[RPW], z2b[RPW], z3a[RPW], z3b[RPW];
#pragma unroll
        for (int r = 0; r < RPW; ++r) { z2a[r] = 0.f; z2b[r] = 0.f; z3a[r] = 0.f; z3b[r] = 0.f; }
        mvf2(Wq, Sa, Sb, lane, z2a, z2b, z3a, z3b);   // zdot = W2 pdot

#pragma unroll
        for (int r = 0; r < RPW; ++r) {
            const float zd20 = z2a[r], zd21 = z2b[r];
            const float zd30 = z3a[r], zd31 = z3b[r];
            const float sg2 = dppred(fmaf(q0[r], zd20, q1[r] * zd21));
            const float sg3 = dppred(fmaf(q0[r], zd30, q1[r] * zd31));
            const float qd20 = q0[r] * (zd20 - sg2), qd21 = q1[r] * (zd21 - sg2);
            const float qd30 = q0[r] * (zd30 - sg3), qd31 = q1[r] * (zd31 - sg3);
            const float sd2 = dppred(fmaf(w3a, qd20, w3b * qd21));
            const float sd3 = dppred(fmaf(w3a, qd30, w3b * qd31));
            Sa[r * 128 + lane]      = fmaf(qd20, w3a - sw[r], -(q0[r] * sd2));  // udot2
            Sa[r * 128 + 64 + lane] = fmaf(qd21, w3b - sw[r], -(q1[r] * sd2));
            Sb[r * 128 + lane]      = fmaf(qd30, w3a - sw[r], -(q0[r] * sd3));  // udot3
            Sb[r * 128 + 64 + lane] = fmaf(qd31, w3b - sw[r], -(q1[r] * sd3));
        }
#pragma unroll
        for (int r = 0; r < RPW; ++r) { z2a[r] = 0.f; z2b[r] = 0.f; z3a[r] = 0.f; z3b[r] = 0.f; }
        mvt2(Wq, Sa, Sb, lane, z2a, z2b, z3a, z3b);   // vdot = W2^T udot

#pragma unroll
        for (int r = 0; r < RPW; ++r) {
            const float vd20 = z2a[r], vd21 = z2b[r];
            const float vd30 = z3a[r], vd31 = z3b[r];
            const float dpv2 = dppred(fmaf(pd20[r], v0[r], fmaf(pd21[r], v1[r],
                               fmaf(p0[r], vd20, p1[r] * vd21))));
            const float dpv3 = dppred(fmaf(pd30[r], v0[r], fmaf(pd31[r], v1[r],
                               fmaf(p0[r], vd30, p1[r] * vd31))));
            const float gd20 = fmaf(pd20[r], v0[r] - pv[r], p0[r] * (vd20 - dpv2));
            const float gd21 = fmaf(pd21[r], v1[r] - pv[r], p1[r] * (vd21 - dpv2));
            const float gd30 = fmaf(pd30[r], v0[r] - pv[r], p0[r] * (vd30 - dpv3));
            const float gd31 = fmaf(pd31[r], v1[r] - pv[r], p1[r] * (vd31 - dpv3));
            const float h20 = dppred(fmaf(w1a0, gd20, w1b0 * gd21));
            const float h21 = dppred(fmaf(w1a1, gd20, w1b1 * gd21));
            const float h22 = dppred(fmaf(w1a2, gd20, w1b2 * gd21));
            const float h23 = dppred(fmaf(w1a3, gd20, w1b3 * gd21));
            const float h30 = dppred(fmaf(w1a0, gd30, w1b0 * gd31));
            const float h31 = dppred(fmaf(w1a1, gd30, w1b1 * gd31));
            const float h32 = dppred(fmaf(w1a2, gd30, w1b2 * gd31));
            const float h33 = dppred(fmaf(w1a3, gd30, w1b3 * gd31));

            // ---- 2x2 solve in fp64 (det cancellation is the error amplifier)
            const double rhs0 = (double)g0[r] - ((double)h20 * (double)X2[r] + (double)h21 * (double)X3[r]);
            const double rhs1 = (double)g0[r] - ((double)h30 * (double)X2[r] + (double)h31 * (double)X3[r]);
            const double a = (double)h22, b = (double)h32, c = (double)h23, d = (double)h33;
            const double det = a * d - b * c;
            const float t0 = (float)((d * rhs0 - b * rhs1) / det);
            const float t1 = (float)((a * rhs1 - c * rhs0) / det);
            if (lane == 0) {
                ((float4*)gout)[row0 + r] = make_float4(X2[r], X3[r], t0, t1);
            }
        }
    }
}

extern "C" void kernel_launch(void* const* d_in, const int* in_sizes, int n_in,
                              void* d_out, int out_size, void* d_ws, size_t ws_size,
                              hipStream_t stream)
{
    const float* gx  = (const float*)d_in[0];
    const float* gW1 = (const float*)d_in[1];
    const float* gb1 = (const float*)d_in[2];
    const float* gW2 = (const float*)d_in[3];
    const float* gb2 = (const float*)d_in[4];
    const float* gW3 = (const float*)d_in[5];
    float* gout = (float*)d_out;

    (void)hipFuncSetAttribute((const void*)lnn_kernel,
                              hipFuncAttributeMaxDynamicSharedMemorySize, LDS_BYTES);
    lnn_kernel<<<NGRID, NTHREADS, LDS_BYTES, stream>>>(gx, gW1, gb1, gW2, gb2, gW3, gout);
}

// Round 8
// 1094.880 us; speedup vs baseline: 1.3054x; 1.0850x over previous
//
#include <hip/hip_runtime.h>

// LNN_50302656971188 — batched grad + partial-Hessian of 2-layer softmax MLP + 2x2 solve.
// R8: R7 is co-bound (VALU busy ~990us/SIMD, LDS pipe ~0.9-1.3ms/CU) with ~300us of
// no-issue bubbles at only 2 waves/SIMD. Fix: 1024-thread block = 16 waves = 4/SIMD
// (RPW 8->4 so staging fits: 66.5KB weights + 64KB staging = 130.5KB). Per-row code
// is numerically IDENTICAL to R7 (R5 precedent: RPW change keeps absmax 5120).
// Quad loops unroll 2->4 (same FMA order, fewer address adds).

#define RPW 4
#define NWAVES 16
#define NTHREADS 1024
#define NGRID 256
#define NITERS 16      // 256 blocks * 16 waves * 4 rows * 16 = 262144
#define QSTRIDE 65
#define QSIZE (64 * QSTRIDE)                              // 4160 floats per quadrant
#define LDS_FLOATS (4 * QSIZE + NWAVES * 2 * RPW * 128)   // 16640 + 16384 = 33024
#define LDS_BYTES (LDS_FLOATS * 4)                        // 132096 B

__device__ __forceinline__ float rlane(float v, int l) {
    return __int_as_float(__builtin_amdgcn_readlane(__float_as_int(v), l));
}

// full-wave (64) sum reduction via DPP, result uniform (identical since R3: absmax-safe)
__device__ __forceinline__ float dppred(float x) {
    x += __int_as_float(__builtin_amdgcn_update_dpp(0, __float_as_int(x), 0x111, 0xf, 0xf, true)); // row_shr:1
    x += __int_as_float(__builtin_amdgcn_update_dpp(0, __float_as_int(x), 0x112, 0xf, 0xf, true)); // row_shr:2
    x += __int_as_float(__builtin_amdgcn_update_dpp(0, __float_as_int(x), 0x114, 0xf, 0xf, true)); // row_shr:4
    x += __int_as_float(__builtin_amdgcn_update_dpp(0, __float_as_int(x), 0x118, 0xf, 0xf, true)); // row_shr:8
    x += __int_as_float(__builtin_amdgcn_update_dpp(0, __float_as_int(x), 0x142, 0xa, 0xf, true)); // bcast15
    x += __int_as_float(__builtin_amdgcn_update_dpp(0, __float_as_int(x), 0x143, 0xc, 0xf, true)); // bcast31
    return rlane(x, 63);
}

// Quadrant layout: Wq[(a*2+b)*QSIZE + r*QSTRIDE + c] = W2[a*64+r][b*64+c]

// ---- forward: z_cA += W2[lane][j] s_j ; z_cB += W2[lane+64][j] s_j ; j = 0..63 then 64..127
__device__ __forceinline__ void mvf(const float* __restrict__ Wq,
                                    const float* __restrict__ S, int lane,
                                    float (&za)[RPW], float (&zb)[RPW])
{
    const float* w00 = Wq + 0 * QSIZE + lane * QSTRIDE;
    const float* w01 = Wq + 1 * QSIZE + lane * QSTRIDE;
    const float* w10 = Wq + 2 * QSIZE + lane * QSTRIDE;
    const float* w11 = Wq + 3 * QSIZE + lane * QSTRIDE;
#pragma unroll 4
    for (int j = 0; j < 64; j += 4) {
        const float a0 = w00[j], a1 = w00[j+1], a2 = w00[j+2], a3 = w00[j+3];
        const float b0 = w10[j], b1 = w10[j+1], b2 = w10[j+2], b3 = w10[j+3];
#pragma unroll
        for (int r = 0; r < RPW; ++r) {
            const float4 s4 = *(const float4*)(S + r * 128 + j);   // broadcast
            za[r] = fmaf(a0, s4.x, za[r]); za[r] = fmaf(a1, s4.y, za[r]);
            za[r] = fmaf(a2, s4.z, za[r]); za[r] = fmaf(a3, s4.w, za[r]);
            zb[r] = fmaf(b0, s4.x, zb[r]); zb[r] = fmaf(b1, s4.y, zb[r]);
            zb[r] = fmaf(b2, s4.z, zb[r]); zb[r] = fmaf(b3, s4.w, zb[r]);
        }
    }
#pragma unroll 4
    for (int j = 0; j < 64; j += 4) {
        const float a0 = w01[j], a1 = w01[j+1], a2 = w01[j+2], a3 = w01[j+3];
        const float b0 = w11[j], b1 = w11[j+1], b2 = w11[j+2], b3 = w11[j+3];
#pragma unroll
        for (int r = 0; r < RPW; ++r) {
            const float4 s4 = *(const float4*)(S + r * 128 + 64 + j);
            za[r] = fmaf(a0, s4.x, za[r]); za[r] = fmaf(a1, s4.y, za[r]);
            za[r] = fmaf(a2, s4.z, za[r]); za[r] = fmaf(a3, s4.w, za[r]);
            zb[r] = fmaf(b0, s4.x, zb[r]); zb[r] = fmaf(b1, s4.y, zb[r]);
            zb[r] = fmaf(b2, s4.z, zb[r]); zb[r] = fmaf(b3, s4.w, zb[r]);
        }
    }
}

// dual-s forward (weights read once for two s-vectors)
__device__ __forceinline__ void mvf2(const float* __restrict__ Wq,
                                     const float* __restrict__ SA,
                                     const float* __restrict__ SB, int lane,
                                     float (&zAa)[RPW], float (&zAb)[RPW],
                                     float (&zBa)[RPW], float (&zBb)[RPW])
{
    const float* w00 = Wq + 0 * QSIZE + lane * QSTRIDE;
    const float* w01 = Wq + 1 * QSIZE + lane * QSTRIDE;
    const float* w10 = Wq + 2 * QSIZE + lane * QSTRIDE;
    const float* w11 = Wq + 3 * QSIZE + lane * QSTRIDE;
#pragma unroll 4
    for (int j = 0; j < 64; j += 4) {
        const float a0 = w00[j], a1 = w00[j+1], a2 = w00[j+2], a3 = w00[j+3];
        const float b0 = w10[j], b1 = w10[j+1], b2 = w10[j+2], b3 = w10[j+3];
#pragma unroll
        for (int r = 0; r < RPW; ++r) {
            const float4 x4 = *(const float4*)(SA + r * 128 + j);
            const float4 y4 = *(const float4*)(SB + r * 128 + j);
            zAa[r] = fmaf(a0, x4.x, zAa[r]); zAa[r] = fmaf(a1, x4.y, zAa[r]);
            zAa[r] = fmaf(a2, x4.z, zAa[r]); zAa[r] = fmaf(a3, x4.w, zAa[r]);
            zAb[r] = fmaf(b0, x4.x, zAb[r]); zAb[r] = fmaf(b1, x4.y, zAb[r]);
            zAb[r] = fmaf(b2, x4.z, zAb[r]); zAb[r] = fmaf(b3, x4.w, zAb[r]);
            zBa[r] = fmaf(a0, y4.x, zBa[r]); zBa[r] = fmaf(a1, y4.y, zBa[r]);
            zBa[r] = fmaf(a2, y4.z, zBa[r]); zBa[r] = fmaf(a3, y4.w, zBa[r]);
            zBb[r] = fmaf(b0, y4.x, zBb[r]); zBb[r] = fmaf(b1, y4.y, zBb[r]);
            zBb[r] = fmaf(b2, y4.z, zBb[r]); zBb[r] = fmaf(b3, y4.w, zBb[r]);
        }
    }
#pragma unroll 4
    for (int j = 0; j < 64; j += 4) {
        const float a0 = w01[j], a1 = w01[j+1], a2 = w01[j+2], a3 = w01[j+3];
        const float b0 = w11[j], b1 = w11[j+1], b2 = w11[j+2], b3 = w11[j+3];
#pragma unroll
        for (int r = 0; r < RPW; ++r) {
            const float4 x4 = *(const float4*)(SA + r * 128 + 64 + j);
            const float4 y4 = *(const float4*)(SB + r * 128 + 64 + j);
            zAa[r] = fmaf(a0, x4.x, zAa[r]); zAa[r] = fmaf(a1, x4.y, zAa[r]);
            zAa[r] = fmaf(a2, x4.z, zAa[r]); zAa[r] = fmaf(a3, x4.w, zAa[r]);
            zAb[r] = fmaf(b0, x4.x, zAb[r]); zAb[r] = fmaf(b1, x4.y, zAb[r]);
            zAb[r] = fmaf(b2, x4.z, zAb[r]); zAb[r] = fmaf(b3, x4.w, zAb[r]);
            zBa[r] = fmaf(a0, y4.x, zBa[r]); zBa[r] = fmaf(a1, y4.y, zBa[r]);
            zBa[r] = fmaf(a2, y4.z, zBa[r]); zBa[r] = fmaf(a3, y4.w, zBa[r]);
            zBb[r] = fmaf(b0, y4.x, zBb[r]); zBb[r] = fmaf(b1, y4.y, zBb[r]);
            zBb[r] = fmaf(b2, y4.z, zBb[r]); zBb[r] = fmaf(b3, y4.w, zBb[r]);
        }
    }
}

// ---- transpose: v_cA += W2[i][lane] u_i ; v_cB += W2[i][lane+64] u_i ; i = 0..63 then 64..127
__device__ __forceinline__ void mvt(const float* __restrict__ Wq,
                                    const float* __restrict__ S, int lane,
                                    float (&za)[RPW], float (&zb)[RPW])
{
    const float* t00 = Wq + 0 * QSIZE + lane;   // col lane of Q00 (rows 0..63)
    const float* t01 = Wq + 1 * QSIZE + lane;   // col lane of Q01 (= col lane+64 of W2)
    const float* t10 = Wq + 2 * QSIZE + lane;   // rows 64..127, col lane
    const float* t11 = Wq + 3 * QSIZE + lane;
#pragma unroll 4
    for (int i = 0; i < 64; i += 4) {
        const float a0 = t00[(i+0)*QSTRIDE], a1 = t00[(i+1)*QSTRIDE],
                    a2 = t00[(i+2)*QSTRIDE], a3 = t00[(i+3)*QSTRIDE];
        const float b0 = t01[(i+0)*QSTRIDE], b1 = t01[(i+1)*QSTRIDE],
                    b2 = t01[(i+2)*QSTRIDE], b3 = t01[(i+3)*QSTRIDE];
#pragma unroll
        for (int r = 0; r < RPW; ++r) {
            const float4 u4 = *(const float4*)(S + r * 128 + i);
            za[r] = fmaf(a0, u4.x, za[r]); za[r] = fmaf(a1, u4.y, za[r]);
            za[r] = fmaf(a2, u4.z, za[r]); za[r] = fmaf(a3, u4.w, za[r]);
            zb[r] = fmaf(b0, u4.x, zb[r]); zb[r] = fmaf(b1, u4.y, zb[r]);
            zb[r] = fmaf(b2, u4.z, zb[r]); zb[r] = fmaf(b3, u4.w, zb[r]);
        }
    }
#pragma unroll 4
    for (int i = 0; i < 64; i += 4) {
        const float a0 = t10[(i+0)*QSTRIDE], a1 = t10[(i+1)*QSTRIDE],
                    a2 = t10[(i+2)*QSTRIDE], a3 = t10[(i+3)*QSTRIDE];
        const float b0 = t11[(i+0)*QSTRIDE], b1 = t11[(i+1)*QSTRIDE],
                    b2 = t11[(i+2)*QSTRIDE], b3 = t11[(i+3)*QSTRIDE];
#pragma unroll
        for (int r = 0; r < RPW; ++r) {
            const float4 u4 = *(const float4*)(S + r * 128 + 64 + i);
            za[r] = fmaf(a0, u4.x, za[r]); za[r] = fmaf(a1, u4.y, za[r]);
            za[r] = fmaf(a2, u4.z, za[r]); za[r] = fmaf(a3, u4.w, za[r]);
            zb[r] = fmaf(b0, u4.x, zb[r]); zb[r] = fmaf(b1, u4.y, zb[r]);
            zb[r] = fmaf(b2, u4.z, zb[r]); zb[r] = fmaf(b3, u4.w, zb[r]);
        }
    }
}

__device__ __forceinline__ void mvt2(const float* __restrict__ Wq,
                                     const float* __restrict__ SA,
                                     const float* __restrict__ SB, int lane,
                                     float (&zAa)[RPW], float (&zAb)[RPW],
                                     float (&zBa)[RPW], float (&zBb)[RPW])
{
    const float* t00 = Wq + 0 * QSIZE + lane;
    const float* t01 = Wq + 1 * QSIZE + lane;
    const float* t10 = Wq + 2 * QSIZE + lane;
    const float* t11 = Wq + 3 * QSIZE + lane;
#pragma unroll 4
    for (int i = 0; i < 64; i += 4) {
        const float a0 = t00[(i+0)*QSTRIDE], a1 = t00[(i+1)*QSTRIDE],
                    a2 = t00[(i+2)*QSTRIDE], a3 = t00[(i+3)*QSTRIDE];
        const float b0 = t01[(i+0)*QSTRIDE], b1 = t01[(i+1)*QSTRIDE],
                    b2 = t01[(i+2)*QSTRIDE], b3 = t01[(i+3)*QSTRIDE];
#pragma unroll
        for (int r = 0; r < RPW; ++r) {
            const float4 x4 = *(const float4*)(SA + r * 128 + i);
            const float4 y4 = *(const float4*)(SB + r * 128 + i);
            zAa[r] = fmaf(a0, x4.x, zAa[r]); zAa[r] = fmaf(a1, x4.y, zAa[r]);
            zAa[r] = fmaf(a2, x4.z, zAa[r]); zAa[r] = fmaf(a3, x4.w, zAa[r]);
            zAb[r] = fmaf(b0, x4.x, zAb[r]); zAb[r] = fmaf(b1, x4.y, zAb[r]);
            zAb[r] = fmaf(b2, x4.z, zAb[r]); zAb[r] = fmaf(b3, x4.w, zAb[r]);
            zBa[r] = fmaf(a0, y4.x, zBa[r]); zBa[r] = fmaf(a1, y4.y, zBa[r]);
            zBa[r] = fmaf(a2, y4.z, zBa[r]); zBa[r] = fmaf(a3, y4.w, zBa[r]);
            zBb[r] = fmaf(b0, y4.x, zBb[r]); zBb[r] = fmaf(b1, y4.y, zBb[r]);
            zBb[r] = fmaf(b2, y4.z, zBb[r]); zBb[r] = fmaf(b3, y4.w, zBb[r]);
        }
    }
#pragma unroll 4
    for (int i = 0; i < 64; i += 4) {
        const float a0 = t10[(i+0)*QSTRIDE], a1 = t10[(i+1)*QSTRIDE],
                    a2 = t10[(i+2)*QSTRIDE], a3 = t10[(i+3)*QSTRIDE];
        const float b0 = t11[(i+0)*QSTRIDE], b1 = t11[(i+1)*QSTRIDE],
                    b2 = t11[(i+2)*QSTRIDE], b3 = t11[(i+3)*QSTRIDE];
#pragma unroll
        for (int r = 0; r < RPW; ++r) {
            const float4 x4 = *(const float4*)(SA + r * 128 + 64 + i);
            const float4 y4 = *(const float4*)(SB + r * 128 + 64 + i);
            zAa[r] = fmaf(a0, x4.x, zAa[r]); zAa[r] = fmaf(a1, x4.y, zAa[r]);
            zAa[r] = fmaf(a2, x4.z, zAa[r]); zAa[r] = fmaf(a3, x4.w, zAa[r]);
            zAb[r] = fmaf(b0, x4.x, zAb[r]); zAb[r] = fmaf(b1, x4.y, zAb[r]);
            zAb[r] = fmaf(b2, x4.z, zAb[r]); zAb[r] = fmaf(b3, x4.w, zAb[r]);
            zBa[r] = fmaf(a0, y4.x, zBa[r]); zBa[r] = fmaf(a1, y4.y, zBa[r]);
            zBa[r] = fmaf(a2, y4.z, zBa[r]); zBa[r] = fmaf(a3, y4.w, zBa[r]);
            zBb[r] = fmaf(b0, y4.x, zBb[r]); zBb[r] = fmaf(b1, y4.y, zBb[r]);
            zBb[r] = fmaf(b2, y4.z, zBb[r]); zBb[r] = fmaf(b3, y4.w, zBb[r]);
        }
    }
}

extern "C" __global__ __launch_bounds__(NTHREADS, 4)
void lnn_kernel(const float* __restrict__ gx, const float* __restrict__ gW1,
                const float* __restrict__ gb1, const float* __restrict__ gW2,
                const float* __restrict__ gb2, const float* __restrict__ gW3,
                float* __restrict__ gout)
{
    extern __shared__ float lds[];
    float* Wq  = lds;                     // 4 quadrants, each [64][QSTRIDE]
    float* Sst = lds + 4 * QSIZE;         // [NWAVES][2][RPW][128] staging

    const int tid  = threadIdx.x;
    const int lane = tid & 63;
    const int wv   = tid >> 6;

    for (int e = tid; e < 16384; e += NTHREADS) {
        const int i = e >> 7, j = e & 127;
        Wq[((i >> 6) * 2 + (j >> 6)) * QSIZE + (i & 63) * QSTRIDE + (j & 63)] = gW2[e];
    }

    const int cA = lane, cB = lane + 64;
    const float w1a0 = gW1[cA * 4 + 0], w1a1 = gW1[cA * 4 + 1],
                w1a2 = gW1[cA * 4 + 2], w1a3 = gW1[cA * 4 + 3];
    const float w1b0 = gW1[cB * 4 + 0], w1b1 = gW1[cB * 4 + 1],
                w1b2 = gW1[cB * 4 + 2], w1b3 = gW1[cB * 4 + 3];
    const float b1a = gb1[cA], b1b = gb1[cB];
    const float b2a = gb2[cA], b2b = gb2[cB];
    const float w3a = gW3[cA], w3b = gW3[cB];

    __syncthreads();   // weights staged; Sa/Sb below are wave-private

    float* Sa = Sst + wv * (2 * RPW * 128);
    float* Sb = Sa + RPW * 128;

#pragma unroll 1
    for (int it = 0; it < NITERS; ++it) {
        const int row0 = blockIdx.x * (NITERS * NWAVES * RPW) + it * (NWAVES * RPW) + wv * RPW;

        float p0[RPW], p1[RPW], q0[RPW], q1[RPW], v0[RPW], v1[RPW];
        float X2[RPW], X3[RPW];
        float sw[RPW], pv[RPW], g0[RPW];

        // ---- layer 1: p = softmax(W1 x + b1); stage p into Sa
#pragma unroll
        for (int r = 0; r < RPW; ++r) {
            const float4 xr = ((const float4*)gx)[row0 + r];
            X2[r] = xr.z; X3[r] = xr.w;
            const float z1a = fmaf(w1a0, xr.x, fmaf(w1a1, xr.y, fmaf(w1a2, xr.z, fmaf(w1a3, xr.w, b1a))));
            const float z1b = fmaf(w1b0, xr.x, fmaf(w1b1, xr.y, fmaf(w1b2, xr.z, fmaf(w1b3, xr.w, b1b))));
            const float ea = __expf(z1a), eb = __expf(z1b);
            const float rs = 1.0f / dppred(ea + eb);
            p0[r] = ea * rs; p1[r] = eb * rs;
            Sa[r * 128 + lane]      = p0[r];
            Sa[r * 128 + 64 + lane] = p1[r];
        }

        // ---- layer 2 forward: z = W2 p + b2 ; q = softmax(z); u = q*(w3 - s)
        float zfa[RPW], zfb[RPW];
#pragma unroll
        for (int r = 0; r < RPW; ++r) { zfa[r] = b2a; zfb[r] = b2b; }
        mvf(Wq, Sa, lane, zfa, zfb);
#pragma unroll
        for (int r = 0; r < RPW; ++r) {
            const float ea = __expf(zfa[r]), eb = __expf(zfb[r]);
            const float rs = 1.0f / dppred(ea + eb);
            q0[r] = ea * rs; q1[r] = eb * rs;
            sw[r] = dppred(fmaf(w3a, q0[r], w3b * q1[r]));
            Sa[r * 128 + lane]      = q0[r] * (w3a - sw[r]);   // u
            Sa[r * 128 + 64 + lane] = q1[r] * (w3b - sw[r]);
        }

        // ---- backward: v = W2^T u ; pv = p.v ; g0 = W1[:,0] . (p*(v-pv))
#pragma unroll
        for (int r = 0; r < RPW; ++r) { zfa[r] = 0.f; zfb[r] = 0.f; }
        mvt(Wq, Sa, lane, zfa, zfb);
#pragma unroll
        for (int r = 0; r < RPW; ++r) {
            v0[r] = zfa[r]; v1[r] = zfb[r];
            pv[r] = dppred(fmaf(p0[r], v0[r], p1[r] * v1[r]));
            g0[r] = dppred(fmaf(w1a0, p0[r] * (v0[r] - pv[r]), w1b0 * (p1[r] * (v1[r] - pv[r]))));
        }

        // ---- dual HVP: tangents t2 = W1[:,2], t3 = W1[:,3]; stage pd2->Sa, pd3->Sb
        float pd20[RPW], pd21[RPW], pd30[RPW], pd31[RPW];
#pragma unroll
        for (int r = 0; r < RPW; ++r) {
            const float pi2 = dppred(fmaf(w1a2, p0[r], w1b2 * p1[r]));
            const float pi3 = dppred(fmaf(w1a3, p0[r], w1b3 * p1[r]));
            pd20[r] = p0[r] * (w1a2 - pi2); pd21[r] = p1[r] * (w1b2 - pi2);
            pd30[r] = p0[r] * (w1a3 - pi3); pd31[r] = p1[r] * (w1b3 - pi3);
            Sa[r * 128 + lane]      = pd20[r];
            Sa[r * 128 + 64 + lane] = pd21[r];
            Sb[r * 128 + lane]      = pd30[r];
            Sb[r * 128 + 64 + lane] = pd31[r];
        }
        float z2a[RPW], z2b[RPW], z3a[RPW], z3b[RPW];
#pragma unroll
        for (int r = 0; r < RPW; ++r) { z2a[r] = 0.f; z2b[r] = 0.f; z3a[r] = 0.f; z3b[r] = 0.f; }
        mvf2(Wq, Sa, Sb, lane, z2a, z2b, z3a, z3b);   // zdot = W2 pdot

#pragma unroll
        for (int r = 0; r < RPW; ++r) {
            const float zd20 = z2a[r], zd21 = z2b[r];
            const float zd30 = z3a[r], zd31 = z3b[r];
            const float sg2 = dppred(fmaf(q0[r], zd20, q1[r] * zd21));
            const float sg3 = dppred(fmaf(q0[r], zd30, q1[r] * zd31));
            const float qd20 = q0[r] * (zd20 - sg2), qd21 = q1[r] * (zd21 - sg2);
            const float qd30 = q0[r] * (zd30 - sg3), qd31 = q1[r] * (zd31 - sg3);
            const float sd2 = dppred(fmaf(w3a, qd20, w3b * qd21));
            const float sd3 = dppred(fmaf(w3a, qd30, w3b * qd31));
            Sa[r * 128 + lane]      = fmaf(qd20, w3a - sw[r], -(q0[r] * sd2));  // udot2
            Sa[r * 128 + 64 + lane] = fmaf(qd21, w3b - sw[r], -(q1[r] * sd2));
            Sb[r * 128 + lane]      = fmaf(qd30, w3a - sw[r], -(q0[r] * sd3));  // udot3
            Sb[r * 128 + 64 + lane] = fmaf(qd31, w3b - sw[r], -(q1[r] * sd3));
        }
#pragma unroll
        for (int r = 0; r < RPW; ++r) { z2a[r] = 0.f; z2b[r] = 0.f; z3a[r] = 0.f; z3b[r] = 0.f; }
        mvt2(Wq, Sa, Sb, lane, z2a, z2b, z3a, z3b);   // vdot = W2^T udot

#pragma unroll
        for (int r = 0; r < RPW; ++r) {
            const float vd20 = z2a[r], vd21 = z2b[r];
            const float vd30 = z3a[r], vd31 = z3b[r];
            const float dpv2 = dppred(fmaf(pd20[r], v0[r], fmaf(pd21[r], v1[r],
                               fmaf(p0[r], vd20, p1[r] * vd21))));
            const float dpv3 = dppred(fmaf(pd30[r], v0[r], fmaf(pd31[r], v1[r],
                               fmaf(p0[r], vd30, p1[r] * vd31))));
            const float gd20 = fmaf(pd20[r], v0[r] - pv[r], p0[r] * (vd20 - dpv2));
            const float gd21 = fmaf(pd21[r], v1[r] - pv[r], p1[r] * (vd21 - dpv2));
            const float gd30 = fmaf(pd30[r], v0[r] - pv[r], p0[r] * (vd30 - dpv3));
            const float gd31 = fmaf(pd31[r], v1[r] - pv[r], p1[r] * (vd31 - dpv3));
            const float h20 = dppred(fmaf(w1a0, gd20, w1b0 * gd21));
            const float h21 = dppred(fmaf(w1a1, gd20, w1b1 * gd21));
            const float h22 = dppred(fmaf(w1a2, gd20, w1b2 * gd21));
            const float h23 = dppred(fmaf(w1a3, gd20, w1b3 * gd21));
            const float h30 = dppred(fmaf(w1a0, gd30, w1b0 * gd31));
            const float h31 = dppred(fmaf(w1a1, gd30, w1b1 * gd31));
            const float h32 = dppred(fmaf(w1a2, gd30, w1b2 * gd31));
            const float h33 = dppred(fmaf(w1a3, gd30, w1b3 * gd31));

            // ---- 2x2 solve in fp64 (det cancellation is the error amplifier)
            const double rhs0 = (double)g0[r] - ((double)h20 * (double)X2[r] + (double)h21 * (double)X3[r]);
            const double rhs1 = (double)g0[r] - ((double)h30 * (double)X2[r] + (double)h31 * (double)X3[r]);
            const double a = (double)h22, b = (double)h32, c = (double)h23, d = (double)h33;
            const double det = a * d - b * c;
            const float t0 = (float)((d * rhs0 - b * rhs1) / det);
            const float t1 = (float)((a * rhs1 - c * rhs0) / det);
            if (lane == 0) {
                ((float4*)gout)[row0 + r] = make_float4(X2[r], X3[r], t0, t1);
            }
        }
    }
}

extern "C" void kernel_launch(void* const* d_in, const int* in_sizes, int n_in,
                              void* d_out, int out_size, void* d_ws, size_t ws_size,
                              hipStream_t stream)
{
    const float* gx  = (const float*)d_in[0];
    const float* gW1 = (const float*)d_in[1];
    const float* gb1 = (const float*)d_in[2];
    const float* gW2 = (const float*)d_in[3];
    const float* gb2 = (const float*)d_in[4];
    const float* gW3 = (const float*)d_in[5];
    float* gout = (float*)d_out;

    (void)hipFuncSetAttribute((const void*)lnn_kernel,
                              hipFuncAttributeMaxDynamicSharedMemorySize, LDS_BYTES);
    lnn_kernel<<<NGRID, NTHREADS, LDS_BYTES, stream>>>(gx, gW1, gb1, gW2, gb2, gW3, gout);
}